// Round 1
// baseline (410.808 us; speedup 1.0000x reference)
//
#include <hip/hip_runtime.h>
#include <hip/hip_bf16.h>

#define B_ 16
#define S_ 4096
#define C_ 320
#define KK_ 77
#define D_ 768
#define H_ 8
#define DH_ 40
#define KP_ 80           // padded keys per head
#define NP_ (H_ * KP_)   // 640
#define TAU_ 0.1f
#define GAMMA_ 1.0f
#define EPS_ 1e-12f

typedef __bf16 bf16x8 __attribute__((ext_vector_type(8)));
typedef float f32x4 __attribute__((ext_vector_type(4)));

__device__ __forceinline__ unsigned short f2bf(float f) {
    union { float f; unsigned u; } v; v.f = f;
    unsigned r = v.u + 0x7fffu + ((v.u >> 16) & 1u);
    return (unsigned short)(r >> 16);
}

// ---------------------------------------------------------------- kv proj
// k = ehs @ Wk, v = ehs @ Wv   -> kbuf/vbuf [B][77][320] f32
__global__ __launch_bounds__(320) void kv_proj(const float* __restrict__ ehs,
        const float* __restrict__ Wk, const float* __restrict__ Wv,
        float* __restrict__ kbuf, float* __restrict__ vbuf) {
    const int b = blockIdx.y;
    const int kk0 = blockIdx.x * 8;
    const int nk = min(8, KK_ - kk0);
    __shared__ float e[8 * D_];
    const int tid = threadIdx.x;
    for (int i = tid; i < nk * D_; i += 320)
        e[i] = ehs[(size_t)(b * KK_ + kk0) * D_ + i];
    __syncthreads();
    const int c = tid;
    float ak[8] = {0.f,0.f,0.f,0.f,0.f,0.f,0.f,0.f};
    float av[8] = {0.f,0.f,0.f,0.f,0.f,0.f,0.f,0.f};
    for (int d = 0; d < D_; ++d) {
        float wk = Wk[(size_t)d * C_ + c], wv = Wv[(size_t)d * C_ + c];
        #pragma unroll
        for (int i = 0; i < 8; ++i) {
            ak[i] += e[i * D_ + d] * wk;
            av[i] += e[i * D_ + d] * wv;
        }
    }
    for (int i = 0; i < nk; ++i) {
        kbuf[(size_t)(b * KK_ + kk0 + i) * C_ + c] = ak[i];
        vbuf[(size_t)(b * KK_ + kk0 + i) * C_ + c] = av[i];
    }
}

// ---------------------------------------------------------------- penalty
// pen[b*77+kk] = gamma * max(cos(ehs_row, harm) - tau, 0)
__global__ __launch_bounds__(256) void penalty_k(const float* __restrict__ ehs,
        const float* __restrict__ harm, float* __restrict__ pen) {
    const int w = threadIdx.x >> 6, l = threadIdx.x & 63;
    const int row = blockIdx.x * 4 + w;
    if (row >= B_ * KK_) return;
    const float* er = ehs + (size_t)row * D_;
    float ss = 0.f, hh = 0.f, dd = 0.f;
    #pragma unroll
    for (int i = 0; i < D_ / 64; ++i) {
        float ev = er[l + i * 64], hv = harm[l + i * 64];
        ss += ev * ev; hh += hv * hv; dd += ev * hv;
    }
    #pragma unroll
    for (int off = 32; off; off >>= 1) {
        ss += __shfl_xor(ss, off);
        hh += __shfl_xor(hh, off);
        dd += __shfl_xor(dd, off);
    }
    if (l == 0) {
        float cs = dd / (fmaxf(sqrtf(ss), EPS_) * fmaxf(sqrtf(hh), EPS_));
        pen[row] = GAMMA_ * fmaxf(cs - TAU_, 0.f);
    }
}

// ---------------------------------------------------------------- Wp build
// Wp[b][n=(h,kk)][c] = scale * sum_d Wq[c, h*40+d] * kbuf[b,kk,h*40+d]   (bf16)
__global__ __launch_bounds__(256) void build_Wp(const float* __restrict__ kbuf,
        const float* __restrict__ Wq, unsigned short* __restrict__ Wp) {
    const int b = blockIdx.x, h = blockIdx.y;
    __shared__ float kh[KK_ * DH_];     // broadcast-read, no pad needed
    __shared__ float Wqh[C_ * 41];      // stride 41 to dodge bank conflicts
    const int tid = threadIdx.x;
    for (int i = tid; i < KK_ * DH_; i += 256) {
        int kk = i / DH_, d = i % DH_;
        kh[kk * DH_ + d] = kbuf[(size_t)(b * KK_ + kk) * C_ + h * DH_ + d];
    }
    for (int i = tid; i < C_ * DH_; i += 256) {
        int c = i / DH_, d = i % DH_;
        Wqh[c * 41 + d] = Wq[(size_t)c * C_ + h * DH_ + d];
    }
    __syncthreads();
    const float scale = 0.15811388300841898f; // 1/sqrt(40)
    for (int i = tid; i < KP_ * C_; i += 256) {
        int kk = i / C_, c = i % C_;
        float s = 0.f;
        if (kk < KK_) {
            #pragma unroll
            for (int d = 0; d < DH_; ++d) s += Wqh[c * 41 + d] * kh[kk * DH_ + d];
            s *= scale;
        }
        Wp[((size_t)b * NP_ + h * KP_ + kk) * C_ + c] = f2bf(s);
    }
}

// ---------------------------------------------------------------- U build
// U[b][c'][n=(h,kk)] = sum_d vbuf[b,kk,h*40+d] * Wo[h*40+d, c']   (bf16)
__global__ __launch_bounds__(256) void build_U(const float* __restrict__ vbuf,
        const float* __restrict__ Wo, unsigned short* __restrict__ U) {
    const int b = blockIdx.x, h = blockIdx.y;
    __shared__ float vh[KK_ * 41];      // stride 41: kk-consecutive reads
    __shared__ float Woh[DH_ * C_];
    const int tid = threadIdx.x;
    for (int i = tid; i < KK_ * DH_; i += 256) {
        int kk = i / DH_, d = i % DH_;
        vh[kk * 41 + d] = vbuf[(size_t)(b * KK_ + kk) * C_ + h * DH_ + d];
    }
    for (int i = tid; i < DH_ * C_; i += 256) {
        Woh[i] = Wo[(size_t)(h * DH_ + i / C_) * C_ + (i % C_)];
    }
    __syncthreads();
    for (int i = tid; i < C_ * KP_; i += 256) {
        int c = i / KP_, kk = i % KP_;
        float s = 0.f;
        if (kk < KK_) {
            #pragma unroll
            for (int d = 0; d < DH_; ++d) s += vh[kk * 41 + d] * Woh[d * C_ + c];
        }
        U[((size_t)b * C_ + c) * NP_ + h * KP_ + kk] = f2bf(s);
    }
}

// ---------------------------------------------------------------- fused attn
// per block: 64 S-rows of one batch. phase1: scores+softmax (wave=head).
// phase2: out = P @ U + bo  (waves partition 2M x 4N).
__global__ __launch_bounds__(512, 2) void fused_attn(
        const float* __restrict__ hs, const unsigned short* __restrict__ Wp,
        const unsigned short* __restrict__ U, const float* __restrict__ pen,
        const float* __restrict__ bo, float* __restrict__ out) {
    const int b = blockIdx.y;
    const int s0 = blockIdx.x * 64;
    __shared__ unsigned short hs_t[64 * 328];   // bf16 hs tile, padded stride
    __shared__ unsigned short P_t[64 * 648];    // bf16 probs, padded stride
    const int tid = threadIdx.x;

    // stage hs tile (f32 -> bf16)
    const float4* hv = (const float4*)(hs + ((size_t)b * S_ + s0) * C_);
    for (int i = tid; i < 64 * C_ / 4; i += 512) {
        float4 v = hv[i];
        int e0 = i * 4, r = e0 / C_, c = e0 % C_;
        ushort4 u;
        u.x = f2bf(v.x); u.y = f2bf(v.y); u.z = f2bf(v.z); u.w = f2bf(v.w);
        *(ushort4*)(&hs_t[r * 328 + c]) = u;
    }
    __syncthreads();

    const int w = tid >> 6, l = tid & 63;
    const int lrow = l & 15, lk = (l >> 4) * 8;

    // ---- phase 1: head h = w
    {
        const int h = w;
        float pv[5];
        #pragma unroll
        for (int nf = 0; nf < 5; ++nf) {
            int kk = nf * 16 + lrow;
            pv[nf] = (kk < KK_) ? pen[b * KK_ + kk] : 0.f;
        }
        f32x4 acc[4][5];
        #pragma unroll
        for (int mf = 0; mf < 4; ++mf)
            #pragma unroll
            for (int nf = 0; nf < 5; ++nf)
                acc[mf][nf] = (f32x4){0.f, 0.f, 0.f, 0.f};
        const unsigned short* WpB = Wp + ((size_t)b * NP_ + h * KP_) * C_;
        for (int ks = 0; ks < C_ / 32; ++ks) {
            bf16x8 af[4], bfr[5];
            #pragma unroll
            for (int mf = 0; mf < 4; ++mf)
                af[mf] = *(const bf16x8*)(&hs_t[(mf * 16 + lrow) * 328 + ks * 32 + lk]);
            #pragma unroll
            for (int nf = 0; nf < 5; ++nf)
                bfr[nf] = *(const bf16x8*)(&WpB[(size_t)(nf * 16 + lrow) * C_ + ks * 32 + lk]);
            #pragma unroll
            for (int mf = 0; mf < 4; ++mf)
                #pragma unroll
                for (int nf = 0; nf < 5; ++nf)
                    acc[mf][nf] = __builtin_amdgcn_mfma_f32_16x16x32_bf16(
                        af[mf], bfr[nf], acc[mf][nf], 0, 0, 0);
        }
        // masked softmax per row (penalty already gamma-scaled)
        #pragma unroll
        for (int mf = 0; mf < 4; ++mf) {
            #pragma unroll
            for (int r = 0; r < 4; ++r) {
                float v0[5]; float m = -1e30f;
                #pragma unroll
                for (int nf = 0; nf < 5; ++nf) {
                    int kk = nf * 16 + lrow;
                    float x = acc[mf][nf][r] - pv[nf];
                    v0[nf] = (kk < KK_) ? x : -1e30f;
                    m = fmaxf(m, v0[nf]);
                }
                #pragma unroll
                for (int off = 8; off; off >>= 1) m = fmaxf(m, __shfl_xor(m, off));
                float s = 0.f;
                #pragma unroll
                for (int nf = 0; nf < 5; ++nf) {
                    float e = __expf(v0[nf] - m);
                    v0[nf] = e; s += e;
                }
                #pragma unroll
                for (int off = 8; off; off >>= 1) s += __shfl_xor(s, off);
                float inv = 1.f / s;
                int row = mf * 16 + (l >> 4) * 4 + r;
                #pragma unroll
                for (int nf = 0; nf < 5; ++nf)
                    P_t[row * 648 + h * KP_ + nf * 16 + lrow] = f2bf(v0[nf] * inv);
            }
        }
    }
    __syncthreads();

    // ---- phase 2: out tile = P @ U + bo
    {
        const int mgrp = w & 1, ngrp = w >> 1;
        const unsigned short* UB = U + ((size_t)b * C_ + ngrp * 80) * NP_;
        f32x4 acc[2][5];
        #pragma unroll
        for (int mf = 0; mf < 2; ++mf)
            #pragma unroll
            for (int nf = 0; nf < 5; ++nf)
                acc[mf][nf] = (f32x4){0.f, 0.f, 0.f, 0.f};
        for (int ks = 0; ks < NP_ / 32; ++ks) {
            bf16x8 af[2], bfr[5];
            #pragma unroll
            for (int mf = 0; mf < 2; ++mf)
                af[mf] = *(const bf16x8*)(&P_t[(mgrp * 32 + mf * 16 + lrow) * 648 + ks * 32 + lk]);
            #pragma unroll
            for (int nf = 0; nf < 5; ++nf)
                bfr[nf] = *(const bf16x8*)(&UB[(size_t)(nf * 16 + lrow) * NP_ + ks * 32 + lk]);
            #pragma unroll
            for (int mf = 0; mf < 2; ++mf)
                #pragma unroll
                for (int nf = 0; nf < 5; ++nf)
                    acc[mf][nf] = __builtin_amdgcn_mfma_f32_16x16x32_bf16(
                        af[mf], bfr[nf], acc[mf][nf], 0, 0, 0);
        }
        float bov[5];
        #pragma unroll
        for (int nf = 0; nf < 5; ++nf) bov[nf] = bo[ngrp * 80 + nf * 16 + lrow];
        float* op = out + ((size_t)b * S_ + s0) * C_;
        #pragma unroll
        for (int mf = 0; mf < 2; ++mf)
            #pragma unroll
            for (int r = 0; r < 4; ++r)
                #pragma unroll
                for (int nf = 0; nf < 5; ++nf)
                    op[(size_t)(mgrp * 32 + mf * 16 + (l >> 4) * 4 + r) * C_ +
                       ngrp * 80 + nf * 16 + lrow] = acc[mf][nf][r] + bov[nf];
    }
}

// ---------------------------------------------------------------- launch
extern "C" void kernel_launch(void* const* d_in, const int* in_sizes, int n_in,
                              void* d_out, int out_size, void* d_ws, size_t ws_size,
                              hipStream_t stream) {
    const float* hs   = (const float*)d_in[0];
    const float* ehs  = (const float*)d_in[1];
    const float* harm = (const float*)d_in[2];
    const float* Wq   = (const float*)d_in[3];
    const float* Wk   = (const float*)d_in[4];
    const float* Wv   = (const float*)d_in[5];
    const float* Wo   = (const float*)d_in[6];
    const float* bo   = (const float*)d_in[7];
    float* out = (float*)d_out;

    char* ws = (char*)d_ws;
    float* kbuf         = (float*)(ws);                 // 16*77*320*4 = 1,576,960
    float* vbuf         = (float*)(ws + 1576960);       // 1,576,960
    float* pen          = (float*)(ws + 3153920);       // 4,928 (pad to 3,158,848)
    unsigned short* Wp  = (unsigned short*)(ws + 3158848);  // 6,553,600
    unsigned short* U   = (unsigned short*)(ws + 9712448);  // 6,553,600
    // total 16,266,048 bytes

    kv_proj <<<dim3(10, 16), 320, 0, stream>>>(ehs, Wk, Wv, kbuf, vbuf);
    penalty_k<<<dim3(308),    256, 0, stream>>>(ehs, harm, pen);
    build_Wp<<<dim3(16, 8),   256, 0, stream>>>(kbuf, Wq, Wp);
    build_U <<<dim3(16, 8),   256, 0, stream>>>(vbuf, Wo, U);
    fused_attn<<<dim3(64, 16), 512, 0, stream>>>(hs, Wp, U, pen, bo, out);
}

// Round 2
// 335.103 us; speedup vs baseline: 1.2259x; 1.2259x over previous
//
#include <hip/hip_runtime.h>
#include <hip/hip_bf16.h>

#define B_ 16
#define S_ 4096
#define C_ 320
#define KK_ 77
#define D_ 768
#define H_ 8
#define DH_ 40
#define KP_ 80           // padded keys per head
#define NP_ (H_ * KP_)   // 640
#define TAU_ 0.1f
#define GAMMA_ 1.0f
#define EPS_ 1e-12f

typedef __bf16 bf16x8 __attribute__((ext_vector_type(8)));
typedef float f32x4 __attribute__((ext_vector_type(4)));

__device__ __forceinline__ unsigned short f2bf(float f) {
    union { float f; unsigned u; } v; v.f = f;
    unsigned r = v.u + 0x7fffu + ((v.u >> 16) & 1u);
    return (unsigned short)(r >> 16);
}

// ---------------------------------------------------------------- build_M
// Bmat[n][Dk] bf16, n = which*2560 + h*320 + c:
//   which=0: scale * sum_d Wk[Dk, h*40+d] * Wq[c, h*40+d]     (score proj)
//   which=1:         sum_d Wv[Dk, h*40+d] * Wo[h*40+d, c]     (output proj)
__global__ __launch_bounds__(256) void build_M(const float* __restrict__ Wq,
        const float* __restrict__ Wk, const float* __restrict__ Wv,
        const float* __restrict__ Wo, unsigned short* __restrict__ Bmat) {
    const int Dk = blockIdx.x * 256 + threadIdx.x;     // 0..767
    const int h = blockIdx.y;
    const int which = blockIdx.z >> 1;
    const int c0 = (blockIdx.z & 1) * 160;
    float a[DH_];
    const float* Arow = (which ? Wv : Wk) + (size_t)Dk * C_ + h * DH_;
    #pragma unroll
    for (int d = 0; d < DH_; ++d) a[d] = Arow[d];
    __shared__ float wlds[80 * 41];
    const float scale = 0.15811388300841898f;  // 1/sqrt(40)
    for (int cc0 = 0; cc0 < 160; cc0 += 80) {
        __syncthreads();
        for (int i = threadIdx.x; i < 80 * DH_; i += 256) {
            int c = i / DH_, d = i % DH_;
            wlds[c * 41 + d] = which
                ? Wo[(size_t)(h * DH_ + d) * C_ + (c0 + cc0 + c)]
                : Wq[(size_t)(c0 + cc0 + c) * C_ + h * DH_ + d];
        }
        __syncthreads();
        for (int c = 0; c < 80; ++c) {
            float s = 0.f;
            #pragma unroll
            for (int d = 0; d < DH_; ++d) s += a[d] * wlds[c * 41 + d];
            if (!which) s *= scale;
            int n = which * 2560 + h * C_ + (c0 + cc0 + c);
            Bmat[(size_t)n * D_ + Dk] = f2bf(s);
        }
    }
}

// ---------------------------------------------------------------- prep_ehs
// ehs f32 -> ehs_bf [16][80][768] bf16 (kk>=77 zero), + penalty (padded to 80)
__global__ __launch_bounds__(256) void prep_ehs(const float* __restrict__ ehs,
        const float* __restrict__ harm, unsigned short* __restrict__ ehs_bf,
        float* __restrict__ pen) {
    const int kk = blockIdx.x, b = blockIdx.y;
    const int tid = threadIdx.x;
    const size_t obase = ((size_t)b * KP_ + kk) * D_;
    if (kk >= KK_) {
        #pragma unroll
        for (int j = 0; j < 3; ++j) ehs_bf[obase + tid + j * 256] = 0;
        if (tid == 0) pen[b * KP_ + kk] = 0.f;
        return;
    }
    const float* er = ehs + ((size_t)b * KK_ + kk) * D_;
    float ss = 0.f, dd = 0.f, hh = 0.f;
    #pragma unroll
    for (int j = 0; j < 3; ++j) {
        float e = er[tid + j * 256], hv = harm[tid + j * 256];
        ehs_bf[obase + tid + j * 256] = f2bf(e);
        ss += e * e; dd += e * hv; hh += hv * hv;
    }
    #pragma unroll
    for (int off = 32; off; off >>= 1) {
        ss += __shfl_xor(ss, off);
        dd += __shfl_xor(dd, off);
        hh += __shfl_xor(hh, off);
    }
    __shared__ float red[4][3];
    const int w = tid >> 6, l = tid & 63;
    if (l == 0) { red[w][0] = ss; red[w][1] = dd; red[w][2] = hh; }
    __syncthreads();
    if (tid == 0) {
        ss = red[0][0] + red[1][0] + red[2][0] + red[3][0];
        dd = red[0][1] + red[1][1] + red[2][1] + red[3][1];
        hh = red[0][2] + red[1][2] + red[2][2] + red[3][2];
        float cs = dd / (fmaxf(sqrtf(ss), EPS_) * fmaxf(sqrtf(hh), EPS_));
        pen[b * KP_ + kk] = GAMMA_ * fmaxf(cs - TAU_, 0.f);
    }
}

// ---------------------------------------------------------------- gemm_WpU
// out[kk][n] = ehs_bf[b] @ Bmat^T ; n<2560 -> Wp[b][(h,kk)][c], else U[b][c'][(h,kk)]
__global__ __launch_bounds__(512) void gemm_WpU(
        const unsigned short* __restrict__ ehs_bf,
        const unsigned short* __restrict__ Bmat,
        unsigned short* __restrict__ Wp, unsigned short* __restrict__ U) {
    const int id = blockIdx.x;               // 640 = 8 xcd * (16 b * 5)
    const int xcd = id & 7, j = id >> 3;     // j 0..79
    const int b = j & 15, nt = xcd + 8 * (j >> 4);   // nt 0..39
    const int w = threadIdx.x >> 6, l = threadIdx.x & 63;
    const int lrow = l & 15, lk = (l >> 4) * 8;
    const int n = nt * 128 + w * 16;
    const unsigned short* A0 = ehs_bf + (size_t)b * KP_ * D_;
    const unsigned short* Brow = Bmat + (size_t)(n + lrow) * D_;
    f32x4 acc[5];
    #pragma unroll
    for (int mf = 0; mf < 5; ++mf) acc[mf] = (f32x4){0.f, 0.f, 0.f, 0.f};
    for (int ks = 0; ks < D_ / 32; ++ks) {
        bf16x8 bfr = *(const bf16x8*)(Brow + ks * 32 + lk);
        #pragma unroll
        for (int mf = 0; mf < 5; ++mf) {
            bf16x8 af = *(const bf16x8*)(A0 + (size_t)(mf * 16 + lrow) * D_ + ks * 32 + lk);
            acc[mf] = __builtin_amdgcn_mfma_f32_16x16x32_bf16(af, bfr, acc[mf], 0, 0, 0);
        }
    }
    const int col = n + lrow;                // n-window of 16 never crosses h (320%16==0)
    if (col < 2560) {
        const int h = col / C_, c = col % C_;
        #pragma unroll
        for (int mf = 0; mf < 5; ++mf)
            #pragma unroll
            for (int r = 0; r < 4; ++r) {
                int kk = mf * 16 + (l >> 4) * 4 + r;
                Wp[((size_t)b * NP_ + h * KP_ + kk) * C_ + c] = f2bf(acc[mf][r]);
            }
    } else {
        const int n2 = col - 2560;
        const int h = n2 / C_, c = n2 % C_;
        #pragma unroll
        for (int mf = 0; mf < 5; ++mf)
            #pragma unroll
            for (int r = 0; r < 4; ++r) {
                int kk = mf * 16 + (l >> 4) * 4 + r;
                U[((size_t)b * C_ + c) * NP_ + h * KP_ + kk] = f2bf(acc[mf][r]);
            }
    }
}

// ---------------------------------------------------------------- fused attn
// 64 S-rows per block. LDS union: phase1 hs-tile (stride 328), then P (stride
// 640, XOR-swizzled). 81920 B -> 2 blocks/CU.
__global__ __launch_bounds__(512, 4) void fused_attn(
        const float* __restrict__ hs, const unsigned short* __restrict__ Wp,
        const unsigned short* __restrict__ U, const float* __restrict__ pen,
        const float* __restrict__ bo, float* __restrict__ out) {
    const int id = blockIdx.x;                  // 1024 = 8 xcd * 128
    const int xcd = id & 7, rest = id >> 3;
    const int x = rest & 63;
    const int b = xcd * 2 + (rest >> 6);        // 2 batches per XCD -> L2-resident Wp/U
    const int s0 = x * 64;
    __shared__ unsigned short uni[64 * 640];    // 81920 B
    const int tid = threadIdx.x;

    // stage hs tile (f32 -> bf16), stride 328
    const float4* hv = (const float4*)(hs + ((size_t)b * S_ + s0) * C_);
    #pragma unroll
    for (int it = 0; it < 10; ++it) {
        int i = tid + it * 512;
        float4 v = hv[i];
        int e0 = i * 4, r = e0 / C_, c = e0 % C_;
        ushort4 u;
        u.x = f2bf(v.x); u.y = f2bf(v.y); u.z = f2bf(v.z); u.w = f2bf(v.w);
        *(ushort4*)(&uni[r * 328 + c]) = u;
    }
    __syncthreads();

    const int w = tid >> 6, l = tid & 63;
    const int lrow = l & 15, lk = (l >> 4) * 8;

    f32x4 acc[4][5];
    // ---- phase 1: head h = w, scores + softmax (probs left in acc)
    {
        const int h = w;
        #pragma unroll
        for (int mf = 0; mf < 4; ++mf)
            #pragma unroll
            for (int nf = 0; nf < 5; ++nf)
                acc[mf][nf] = (f32x4){0.f, 0.f, 0.f, 0.f};
        const unsigned short* WpB = Wp + ((size_t)b * NP_ + h * KP_) * C_;
        for (int ks = 0; ks < C_ / 32; ++ks) {
            bf16x8 af[4], bfr[5];
            #pragma unroll
            for (int mf = 0; mf < 4; ++mf)
                af[mf] = *(const bf16x8*)(&uni[(mf * 16 + lrow) * 328 + ks * 32 + lk]);
            #pragma unroll
            for (int nf = 0; nf < 5; ++nf)
                bfr[nf] = *(const bf16x8*)(&WpB[(size_t)(nf * 16 + lrow) * C_ + ks * 32 + lk]);
            #pragma unroll
            for (int mf = 0; mf < 4; ++mf)
                #pragma unroll
                for (int nf = 0; nf < 5; ++nf)
                    acc[mf][nf] = __builtin_amdgcn_mfma_f32_16x16x32_bf16(
                        af[mf], bfr[nf], acc[mf][nf], 0, 0, 0);
        }
        float pv[5];
        #pragma unroll
        for (int nf = 0; nf < 5; ++nf) pv[nf] = pen[b * KP_ + nf * 16 + lrow];
        #pragma unroll
        for (int mf = 0; mf < 4; ++mf) {
            #pragma unroll
            for (int r = 0; r < 4; ++r) {
                float v0[5]; float m = -1e30f;
                #pragma unroll
                for (int nf = 0; nf < 5; ++nf) {
                    int kk = nf * 16 + lrow;
                    float xv = acc[mf][nf][r] - pv[nf];
                    v0[nf] = (kk < KK_) ? xv : -1e30f;
                    m = fmaxf(m, v0[nf]);
                }
                #pragma unroll
                for (int off = 8; off; off >>= 1) m = fmaxf(m, __shfl_xor(m, off));
                float s = 0.f;
                #pragma unroll
                for (int nf = 0; nf < 5; ++nf) {
                    float e = __expf(v0[nf] - m);
                    v0[nf] = e; s += e;
                }
                #pragma unroll
                for (int off = 8; off; off >>= 1) s += __shfl_xor(s, off);
                float inv = 1.f / s;
                #pragma unroll
                for (int nf = 0; nf < 5; ++nf) acc[mf][nf][r] = v0[nf] * inv;
            }
        }
    }
    __syncthreads();   // everyone done reading hs region

    // write P bf16 into union, XOR swizzle (row*1280 + off) ^ ((row&7)<<4)
    {
        char* base = (char*)uni;
        #pragma unroll
        for (int mf = 0; mf < 4; ++mf)
            #pragma unroll
            for (int r = 0; r < 4; ++r) {
                int row = mf * 16 + (l >> 4) * 4 + r;
                #pragma unroll
                for (int nf = 0; nf < 5; ++nf) {
                    int col = w * KP_ + nf * 16 + lrow;
                    int a = (row * 1280 + col * 2) ^ ((row & 7) << 4);
                    *(unsigned short*)(base + a) = f2bf(acc[mf][nf][r]);
                }
            }
    }
    __syncthreads();

    // ---- phase 2: out = P @ U + bo  (waves: 2 m-groups x 4 n-groups)
    {
        const int mgrp = w & 1, ngrp = w >> 1;
        const unsigned short* UB = U + ((size_t)b * C_ + ngrp * 80) * NP_;
        f32x4 acc2[2][5];
        #pragma unroll
        for (int mf = 0; mf < 2; ++mf)
            #pragma unroll
            for (int nf = 0; nf < 5; ++nf)
                acc2[mf][nf] = (f32x4){0.f, 0.f, 0.f, 0.f};
        char* base = (char*)uni;
        for (int ks = 0; ks < NP_ / 32; ++ks) {
            bf16x8 af[2], bfr[5];
            #pragma unroll
            for (int mf = 0; mf < 2; ++mf) {
                int row = mgrp * 32 + mf * 16 + lrow;
                int a = (row * 1280 + (ks * 32 + lk) * 2) ^ ((row & 7) << 4);
                af[mf] = *(const bf16x8*)(base + a);
            }
            #pragma unroll
            for (int nf = 0; nf < 5; ++nf)
                bfr[nf] = *(const bf16x8*)(&UB[(size_t)(nf * 16 + lrow) * NP_ + ks * 32 + lk]);
            #pragma unroll
            for (int mf = 0; mf < 2; ++mf)
                #pragma unroll
                for (int nf = 0; nf < 5; ++nf)
                    acc2[mf][nf] = __builtin_amdgcn_mfma_f32_16x16x32_bf16(
                        af[mf], bfr[nf], acc2[mf][nf], 0, 0, 0);
        }
        float bov[5];
        #pragma unroll
        for (int nf = 0; nf < 5; ++nf) bov[nf] = bo[ngrp * 80 + nf * 16 + lrow];
        float* op = out + ((size_t)b * S_ + s0) * C_;
        #pragma unroll
        for (int mf = 0; mf < 2; ++mf)
            #pragma unroll
            for (int r = 0; r < 4; ++r)
                #pragma unroll
                for (int nf = 0; nf < 5; ++nf)
                    op[(size_t)(mgrp * 32 + mf * 16 + (l >> 4) * 4 + r) * C_ +
                       ngrp * 80 + nf * 16 + lrow] = acc2[mf][nf][r] + bov[nf];
    }
}

// ---------------------------------------------------------------- launch
extern "C" void kernel_launch(void* const* d_in, const int* in_sizes, int n_in,
                              void* d_out, int out_size, void* d_ws, size_t ws_size,
                              hipStream_t stream) {
    const float* hs   = (const float*)d_in[0];
    const float* ehs  = (const float*)d_in[1];
    const float* harm = (const float*)d_in[2];
    const float* Wq   = (const float*)d_in[3];
    const float* Wk   = (const float*)d_in[4];
    const float* Wv   = (const float*)d_in[5];
    const float* Wo   = (const float*)d_in[6];
    const float* bo   = (const float*)d_in[7];
    float* out = (float*)d_out;

    char* ws = (char*)d_ws;
    unsigned short* ehs_bf = (unsigned short*)(ws);             //  1,966,080
    unsigned short* Bmat   = (unsigned short*)(ws + 1966080);   //  7,864,320
    float*          pen    = (float*)        (ws + 9830400);    //      5,120
    unsigned short* Wp     = (unsigned short*)(ws + 9835520);   //  6,553,600
    unsigned short* U      = (unsigned short*)(ws + 16389120);  //  6,553,600
    // total 22,942,720 bytes

    build_M <<<dim3(3, 8, 4),  256, 0, stream>>>(Wq, Wk, Wv, Wo, Bmat);
    prep_ehs<<<dim3(80, 16),   256, 0, stream>>>(ehs, harm, ehs_bf, pen);
    gemm_WpU<<<dim3(640),      512, 0, stream>>>(ehs_bf, Bmat, Wp, U);
    fused_attn<<<dim3(1024),   512, 0, stream>>>(hs, Wp, U, pen, bo, out);
}